// Round 1
// baseline (533.404 us; speedup 1.0000x reference)
//
#include <hip/hip_runtime.h>

// RelationMemory: B=256, D=128, OUT=1e6, K+1=512, MOM=0.5
// d_out layout (f32): outs_t [512,256,128] | outs_s [512,256,128] | mem_v1 [1e6,128] | mem_v2 [1e6,128]

typedef __attribute__((ext_vector_type(8))) short bf16x8;
typedef __attribute__((ext_vector_type(4))) float f32x4;

__device__ __forceinline__ unsigned short f2bf(float f) {
    union { float ff; unsigned u; } v; v.ff = f;
    unsigned u = v.u;
    u += 0x7fffu + ((u >> 16) & 1u);   // RNE
    return (unsigned short)(u >> 16);
}

// ---- convert the 4 inner weight matrices (f32 [128,128] row-major) to bf16 in ws
__global__ void prep_weights(const float* __restrict__ Ws2,
                             const float* __restrict__ Wsv,
                             const float* __restrict__ Wt2,
                             const float* __restrict__ Wtv,
                             unsigned short* __restrict__ wb) {
    int i = blockIdx.x * 256 + threadIdx.x;
    if (i < 16384) {
        wb[i]         = f2bf(Ws2[i]);
        wb[16384 + i] = f2bf(Wsv[i]);
        wb[32768 + i] = f2bf(Wt2[i]);
        wb[49152 + i] = f2bf(Wtv[i]);
    }
}

// ---- aS = v1@Ws1^T + bs1 - bs2 ; aT = v2@Wt1^T + bt1 - bt2   (exact f32)
__global__ void prep_a(const float* __restrict__ v1, const float* __restrict__ v2,
                       const float* __restrict__ Ws1, const float* __restrict__ bs1,
                       const float* __restrict__ bs2,
                       const float* __restrict__ Wt1, const float* __restrict__ bt1,
                       const float* __restrict__ bt2,
                       float* __restrict__ aS, float* __restrict__ aT) {
    __shared__ float vs1[128], vs2[128];
    const int b = blockIdx.x, e = threadIdx.x;
    vs1[e] = v1[b * 128 + e];
    vs2[e] = v2[b * 128 + e];
    __syncthreads();
    float s1 = 0.f, s2 = 0.f;
    const float4* w1 = (const float4*)(Ws1 + e * 128);
    const float4* w2 = (const float4*)(Wt1 + e * 128);
    #pragma unroll
    for (int d4 = 0; d4 < 32; ++d4) {
        float4 a = w1[d4], c = w2[d4];
        s1 += a.x * vs1[d4*4] + a.y * vs1[d4*4+1] + a.z * vs1[d4*4+2] + a.w * vs1[d4*4+3];
        s2 += c.x * vs2[d4*4] + c.y * vs2[d4*4+1] + c.z * vs2[d4*4+2] + c.w * vs2[d4*4+3];
    }
    aS[b * 128 + e] = s1 + bs1[e] - bs2[e];
    aT[b * 128 + e] = s2 + bt1[e] - bt2[e];
}

// ---- fused dual-branch: gather -> (X@W2^T) -> relu(a'-.) -> (H@Wv^T)+bv
// tile = 128 consecutive rows of m = k*256 + b; each of 4 waves owns 32 rows.
__global__ __launch_bounds__(256) void branch_fused(
    const float* __restrict__ memv2, const int* __restrict__ idx,
    const float* __restrict__ aS, const float* __restrict__ aT,
    const unsigned short* __restrict__ wb,
    const float* __restrict__ bsv, const float* __restrict__ btv,
    float* __restrict__ outT, float* __restrict__ outS)
{
    __shared__ unsigned short Xs[128 * 128];  // X tile (bf16, swizzled); reused as H_s
    __shared__ unsigned short Ht[128 * 128];  // H_t

    const int tid  = threadIdx.x;
    const int wv   = tid >> 6, lane = tid & 63;
    const int m0   = blockIdx.x * 128;
    const int b0   = m0 & 255;        // batch base of this tile
    const int kq   = m0 >> 8;         // negatives-index (constant across tile)

    // gather phase: wave wv loads rows [wv*32, wv*32+32); 2 rows per wave-instr
    {
        const int sub = lane >> 5;
        const int c4  = (lane & 31) * 4;
        #pragma unroll
        for (int i = 0; i < 16; ++i) {
            const int r = wv * 32 + i * 2 + sub;
            const int grow = idx[(b0 + r) * 512 + kq];
            const float4 x = *(const float4*)(memv2 + (long)grow * 128 + c4);
            ushort4 u;
            u.x = f2bf(x.x); u.y = f2bf(x.y); u.z = f2bf(x.z); u.w = f2bf(x.w);
            // XOR-swizzle 16B chunks by row to make ds_read_b128 bank-uniform
            *(ushort4*)&Xs[r * 128 + (c4 ^ ((r & 7) * 8))] = u;
        }
    }
    __syncthreads();

    const int r0   = wv * 32;
    const int lrow = lane & 15;
    const int kg   = lane >> 4;

    const unsigned short* Ws2b = wb;
    const unsigned short* Wsvb = wb + 16384;
    const unsigned short* Wt2b = wb + 32768;
    const unsigned short* Wtvb = wb + 49152;

    f32x4 accS[2][8], accT[2][8];
    #pragma unroll
    for (int mf = 0; mf < 2; ++mf)
        #pragma unroll
        for (int nf = 0; nf < 8; ++nf) {
            accS[mf][nf] = (f32x4){0.f, 0.f, 0.f, 0.f};
            accT[mf][nf] = (f32x4){0.f, 0.f, 0.f, 0.f};
        }

    // stage 1: X @ W2^T for both branches (A frags shared)
    #pragma unroll
    for (int kk = 0; kk < 4; ++kk) {
        const int kb = kk * 32 + kg * 8;
        const int ra = r0 + lrow, rb = r0 + 16 + lrow;
        bf16x8 A0 = *(const bf16x8*)&Xs[ra * 128 + (kb ^ ((ra & 7) * 8))];
        bf16x8 A1 = *(const bf16x8*)&Xs[rb * 128 + (kb ^ ((rb & 7) * 8))];
        #pragma unroll
        for (int nf = 0; nf < 8; ++nf) {
            const int e = nf * 16 + lrow;
            bf16x8 Bs = *(const bf16x8*)&Ws2b[e * 128 + kb];
            bf16x8 Bt = *(const bf16x8*)&Wt2b[e * 128 + kb];
            accS[0][nf] = __builtin_amdgcn_mfma_f32_16x16x32_bf16(A0, Bs, accS[0][nf], 0, 0, 0);
            accS[1][nf] = __builtin_amdgcn_mfma_f32_16x16x32_bf16(A1, Bs, accS[1][nf], 0, 0, 0);
            accT[0][nf] = __builtin_amdgcn_mfma_f32_16x16x32_bf16(A0, Bt, accT[0][nf], 0, 0, 0);
            accT[1][nf] = __builtin_amdgcn_mfma_f32_16x16x32_bf16(A1, Bt, accT[1][nf], 0, 0, 0);
        }
    }
    __syncthreads();

    // relu(a' - acc) -> bf16 H tiles (H_s overwrites X; rows are wave-private)
    #pragma unroll
    for (int mf = 0; mf < 2; ++mf) {
        #pragma unroll
        for (int nf = 0; nf < 8; ++nf) {
            const int e = nf * 16 + lrow;
            #pragma unroll
            for (int j = 0; j < 4; ++j) {
                const int rt = r0 + mf * 16 + kg * 4 + j;   // m89-verified C/D layout
                const int b  = b0 + rt;
                float hS = fmaxf(aS[b * 128 + e] - accS[mf][nf][j], 0.f);
                float hT = fmaxf(aT[b * 128 + e] - accT[mf][nf][j], 0.f);
                const int ei = e ^ ((rt & 7) * 8);
                Xs[rt * 128 + ei] = f2bf(hS);
                Ht[rt * 128 + ei] = f2bf(hT);
            }
        }
    }
    __syncthreads();

    // stage 2: H @ Wv^T
    f32x4 oS[2][8], oT[2][8];
    #pragma unroll
    for (int mf = 0; mf < 2; ++mf)
        #pragma unroll
        for (int nf = 0; nf < 8; ++nf) {
            oS[mf][nf] = (f32x4){0.f, 0.f, 0.f, 0.f};
            oT[mf][nf] = (f32x4){0.f, 0.f, 0.f, 0.f};
        }
    #pragma unroll
    for (int kk = 0; kk < 4; ++kk) {
        const int kb = kk * 32 + kg * 8;
        const int ra = r0 + lrow, rb = r0 + 16 + lrow;
        bf16x8 AS0 = *(const bf16x8*)&Xs[ra * 128 + (kb ^ ((ra & 7) * 8))];
        bf16x8 AS1 = *(const bf16x8*)&Xs[rb * 128 + (kb ^ ((rb & 7) * 8))];
        bf16x8 AT0 = *(const bf16x8*)&Ht[ra * 128 + (kb ^ ((ra & 7) * 8))];
        bf16x8 AT1 = *(const bf16x8*)&Ht[rb * 128 + (kb ^ ((rb & 7) * 8))];
        #pragma unroll
        for (int nf = 0; nf < 8; ++nf) {
            const int e = nf * 16 + lrow;
            bf16x8 Bs = *(const bf16x8*)&Wsvb[e * 128 + kb];
            bf16x8 Bt = *(const bf16x8*)&Wtvb[e * 128 + kb];
            oS[0][nf] = __builtin_amdgcn_mfma_f32_16x16x32_bf16(AS0, Bs, oS[0][nf], 0, 0, 0);
            oS[1][nf] = __builtin_amdgcn_mfma_f32_16x16x32_bf16(AS1, Bs, oS[1][nf], 0, 0, 0);
            oT[0][nf] = __builtin_amdgcn_mfma_f32_16x16x32_bf16(AT0, Bt, oT[0][nf], 0, 0, 0);
            oT[1][nf] = __builtin_amdgcn_mfma_f32_16x16x32_bf16(AT1, Bt, oT[1][nf], 0, 0, 0);
        }
    }

    // epilogue: + bias, f32 store (16-lane groups write aligned 64B lines)
    float bvS[8], bvT[8];
    #pragma unroll
    for (int nf = 0; nf < 8; ++nf) {
        bvS[nf] = bsv[nf * 16 + lrow];
        bvT[nf] = btv[nf * 16 + lrow];
    }
    #pragma unroll
    for (int mf = 0; mf < 2; ++mf) {
        #pragma unroll
        for (int nf = 0; nf < 8; ++nf) {
            const int e = nf * 16 + lrow;
            #pragma unroll
            for (int j = 0; j < 4; ++j) {
                const int rt = r0 + mf * 16 + kg * 4 + j;
                const long off = (long)(m0 + rt) * 128 + e;
                outT[off] = oT[mf][nf][j] + bvT[nf];
                outS[off] = oS[mf][nf][j] + bvS[nf];
            }
        }
    }
}

// ---- momentum update + L2-normalize the 256 touched rows (after the full copy).
// numpy fancy-assignment semantics: for duplicate y, LAST occurrence wins.
__global__ void update_mem(const float* __restrict__ v1, const float* __restrict__ v2,
                           const int* __restrict__ y,
                           const float* __restrict__ m1, const float* __restrict__ m2,
                           float* __restrict__ o1, float* __restrict__ o2) {
    __shared__ int s_skip;
    __shared__ float part1[2], part2[2];
    const int b = blockIdx.x, t = threadIdx.x;   // 128 threads = 2 waves
    const int yb = y[b];
    if (t == 0) {
        int sk = 0;
        for (int b2 = b + 1; b2 < 256; ++b2) sk |= (y[b2] == yb);
        s_skip = sk;
    }
    __syncthreads();
    if (s_skip) return;
    float x1 = m1[(long)yb * 128 + t] * 0.5f + v1[b * 128 + t] * 0.5f;
    float x2 = m2[(long)yb * 128 + t] * 0.5f + v2[b * 128 + t] * 0.5f;
    float s1 = x1 * x1, s2 = x2 * x2;
    #pragma unroll
    for (int o = 32; o > 0; o >>= 1) {
        s1 += __shfl_down(s1, o);
        s2 += __shfl_down(s2, o);
    }
    if ((t & 63) == 0) { part1[t >> 6] = s1; part2[t >> 6] = s2; }
    __syncthreads();
    const float n1 = part1[0] + part1[1];
    const float n2 = part2[0] + part2[1];
    o1[(long)yb * 128 + t] = x1 / sqrtf(n1);
    o2[(long)yb * 128 + t] = x2 / sqrtf(n2);
}

extern "C" void kernel_launch(void* const* d_in, const int* in_sizes, int n_in,
                              void* d_out, int out_size, void* d_ws, size_t ws_size,
                              hipStream_t stream) {
    (void)in_sizes; (void)n_in; (void)out_size; (void)ws_size;
    const float* v1  = (const float*)d_in[0];
    const float* v2  = (const float*)d_in[1];
    const int*   y   = (const int*)d_in[2];
    const int*   idx = (const int*)d_in[3];
    const float* mv1 = (const float*)d_in[4];
    const float* mv2 = (const float*)d_in[5];
    const float* Ws1 = (const float*)d_in[6];
    const float* bs1 = (const float*)d_in[7];
    const float* Ws2 = (const float*)d_in[8];
    const float* bs2 = (const float*)d_in[9];
    const float* Wsv = (const float*)d_in[10];
    const float* bsv = (const float*)d_in[11];
    const float* Wt1 = (const float*)d_in[12];
    const float* bt1 = (const float*)d_in[13];
    const float* Wt2 = (const float*)d_in[14];
    const float* bt2 = (const float*)d_in[15];
    const float* Wtv = (const float*)d_in[16];
    const float* btv = (const float*)d_in[17];

    float* outT = (float*)d_out;                 // outs_t
    float* outS = outT + 16777216;               // outs_s
    float* oM1  = outT + 33554432;               // new_mem_v1
    float* oM2  = oM1 + 128000000;               // new_mem_v2

    float* aS = (float*)d_ws;                    // 32768 f32
    float* aT = aS + 32768;                      // 32768 f32
    unsigned short* wb = (unsigned short*)(aT + 32768);  // 4 * 16384 bf16

    prep_weights<<<64, 256, 0, stream>>>(Ws2, Wsv, Wt2, Wtv, wb);
    prep_a<<<256, 128, 0, stream>>>(v1, v2, Ws1, bs1, bs2, Wt1, bt1, bt2, aS, aT);
    branch_fused<<<1024, 256, 0, stream>>>(mv2, idx, aS, aT, wb, bsv, btv, outT, outS);
    hipMemcpyAsync(oM1, mv1, 128000000ull * sizeof(float), hipMemcpyDeviceToDevice, stream);
    hipMemcpyAsync(oM2, mv2, 128000000ull * sizeof(float), hipMemcpyDeviceToDevice, stream);
    update_mem<<<256, 128, 0, stream>>>(v1, v2, y, mv1, mv2, oM1, oM2);
}

// Round 4
// 461.732 us; speedup vs baseline: 1.1552x; 1.1552x over previous
//
#include <hip/hip_runtime.h>

// RelationMemory: B=256, D=128, OUT=1e6, K+1=512, MOM=0.5
// d_out layout (f32): outs_t [512,256,128] | outs_s [512,256,128] | mem_v1 [1e6,128] | mem_v2 [1e6,128]

typedef __attribute__((ext_vector_type(8))) short bf16x8;
typedef __attribute__((ext_vector_type(4))) float f32x4;
typedef __attribute__((ext_vector_type(4))) float fvec4;  // native vec for nontemporal builtins

__device__ __forceinline__ unsigned short f2bf(float f) {
    union { float ff; unsigned u; } v; v.ff = f;
    unsigned u = v.u;
    u += 0x7fffu + ((u >> 16) & 1u);   // RNE
    return (unsigned short)(u >> 16);
}

// ---- convert the 4 inner weight matrices (f32 [128,128] row-major) to bf16 in ws
__global__ void prep_weights(const float* __restrict__ Ws2,
                             const float* __restrict__ Wsv,
                             const float* __restrict__ Wt2,
                             const float* __restrict__ Wtv,
                             unsigned short* __restrict__ wb) {
    int i = blockIdx.x * 256 + threadIdx.x;
    if (i < 16384) {
        wb[i]         = f2bf(Ws2[i]);
        wb[16384 + i] = f2bf(Wsv[i]);
        wb[32768 + i] = f2bf(Wt2[i]);
        wb[49152 + i] = f2bf(Wtv[i]);
    }
}

// ---- aS = v1@Ws1^T + bs1 - bs2 ; aT = v2@Wt1^T + bt1 - bt2   (exact f32)
__global__ void prep_a(const float* __restrict__ v1, const float* __restrict__ v2,
                       const float* __restrict__ Ws1, const float* __restrict__ bs1,
                       const float* __restrict__ bs2,
                       const float* __restrict__ Wt1, const float* __restrict__ bt1,
                       const float* __restrict__ bt2,
                       float* __restrict__ aS, float* __restrict__ aT) {
    __shared__ float vs1[128], vs2[128];
    const int b = blockIdx.x, e = threadIdx.x;
    vs1[e] = v1[b * 128 + e];
    vs2[e] = v2[b * 128 + e];
    __syncthreads();
    float s1 = 0.f, s2 = 0.f;
    const float4* w1 = (const float4*)(Ws1 + e * 128);
    const float4* w2 = (const float4*)(Wt1 + e * 128);
    #pragma unroll
    for (int d4 = 0; d4 < 32; ++d4) {
        float4 a = w1[d4], c = w2[d4];
        s1 += a.x * vs1[d4*4] + a.y * vs1[d4*4+1] + a.z * vs1[d4*4+2] + a.w * vs1[d4*4+3];
        s2 += c.x * vs2[d4*4] + c.y * vs2[d4*4+1] + c.z * vs2[d4*4+2] + c.w * vs2[d4*4+3];
    }
    aS[b * 128 + e] = s1 + bs1[e] - bs2[e];
    aT[b * 128 + e] = s2 + bt1[e] - bt2[e];
}

// ---- branch compute body: gather -> (X@W2^T) -> relu(a'-.) -> (H@Wv^T)+bv
__device__ __forceinline__ void branch_body(
    int blk,
    const float* __restrict__ memv2, const int* __restrict__ idx,
    const float* __restrict__ aS, const float* __restrict__ aT,
    const unsigned short* __restrict__ wb,
    const float* __restrict__ bsv, const float* __restrict__ btv,
    float* __restrict__ outT, float* __restrict__ outS,
    unsigned short* Xs, unsigned short* Ht)
{
    const int tid  = threadIdx.x;
    const int wv   = tid >> 6, lane = tid & 63;
    const int m0   = blk * 128;
    const int b0   = m0 & 255;        // batch base of this tile
    const int kq   = m0 >> 8;         // negatives-index (constant across tile)

    // gather phase: wave wv loads rows [wv*32, wv*32+32); 2 rows per wave-instr
    {
        const int sub = lane >> 5;
        const int c4  = (lane & 31) * 4;
        #pragma unroll
        for (int i = 0; i < 16; ++i) {
            const int r = wv * 32 + i * 2 + sub;
            const int grow = idx[(b0 + r) * 512 + kq];
            const float4 x = *(const float4*)(memv2 + (long)grow * 128 + c4);
            ushort4 u;
            u.x = f2bf(x.x); u.y = f2bf(x.y); u.z = f2bf(x.z); u.w = f2bf(x.w);
            // XOR-swizzle 16B chunks by row to make ds_read_b128 bank-uniform
            *(ushort4*)&Xs[r * 128 + (c4 ^ ((r & 7) * 8))] = u;
        }
    }
    __syncthreads();

    const int r0   = wv * 32;
    const int lrow = lane & 15;
    const int kg   = lane >> 4;

    const unsigned short* Ws2b = wb;
    const unsigned short* Wsvb = wb + 16384;
    const unsigned short* Wt2b = wb + 32768;
    const unsigned short* Wtvb = wb + 49152;

    f32x4 accS[2][8], accT[2][8];
    #pragma unroll
    for (int mf = 0; mf < 2; ++mf)
        #pragma unroll
        for (int nf = 0; nf < 8; ++nf) {
            accS[mf][nf] = (f32x4){0.f, 0.f, 0.f, 0.f};
            accT[mf][nf] = (f32x4){0.f, 0.f, 0.f, 0.f};
        }

    // stage 1: X @ W2^T for both branches (A frags shared)
    #pragma unroll
    for (int kk = 0; kk < 4; ++kk) {
        const int kb = kk * 32 + kg * 8;
        const int ra = r0 + lrow, rb = r0 + 16 + lrow;
        bf16x8 A0 = *(const bf16x8*)&Xs[ra * 128 + (kb ^ ((ra & 7) * 8))];
        bf16x8 A1 = *(const bf16x8*)&Xs[rb * 128 + (kb ^ ((rb & 7) * 8))];
        #pragma unroll
        for (int nf = 0; nf < 8; ++nf) {
            const int e = nf * 16 + lrow;
            bf16x8 Bs = *(const bf16x8*)&Ws2b[e * 128 + kb];
            bf16x8 Bt = *(const bf16x8*)&Wt2b[e * 128 + kb];
            accS[0][nf] = __builtin_amdgcn_mfma_f32_16x16x32_bf16(A0, Bs, accS[0][nf], 0, 0, 0);
            accS[1][nf] = __builtin_amdgcn_mfma_f32_16x16x32_bf16(A1, Bs, accS[1][nf], 0, 0, 0);
            accT[0][nf] = __builtin_amdgcn_mfma_f32_16x16x32_bf16(A0, Bt, accT[0][nf], 0, 0, 0);
            accT[1][nf] = __builtin_amdgcn_mfma_f32_16x16x32_bf16(A1, Bt, accT[1][nf], 0, 0, 0);
        }
    }
    __syncthreads();

    // relu(a' - acc) -> bf16 H tiles (H_s overwrites X; rows are wave-private)
    #pragma unroll
    for (int mf = 0; mf < 2; ++mf) {
        #pragma unroll
        for (int nf = 0; nf < 8; ++nf) {
            const int e = nf * 16 + lrow;
            #pragma unroll
            for (int j = 0; j < 4; ++j) {
                const int rt = r0 + mf * 16 + kg * 4 + j;   // m89-verified C/D layout
                const int b  = b0 + rt;
                float hS = fmaxf(aS[b * 128 + e] - accS[mf][nf][j], 0.f);
                float hT = fmaxf(aT[b * 128 + e] - accT[mf][nf][j], 0.f);
                const int ei = e ^ ((rt & 7) * 8);
                Xs[rt * 128 + ei] = f2bf(hS);
                Ht[rt * 128 + ei] = f2bf(hT);
            }
        }
    }
    __syncthreads();

    // stage 2: H @ Wv^T
    f32x4 oS[2][8], oT[2][8];
    #pragma unroll
    for (int mf = 0; mf < 2; ++mf)
        #pragma unroll
        for (int nf = 0; nf < 8; ++nf) {
            oS[mf][nf] = (f32x4){0.f, 0.f, 0.f, 0.f};
            oT[mf][nf] = (f32x4){0.f, 0.f, 0.f, 0.f};
        }
    #pragma unroll
    for (int kk = 0; kk < 4; ++kk) {
        const int kb = kk * 32 + kg * 8;
        const int ra = r0 + lrow, rb = r0 + 16 + lrow;
        bf16x8 AS0 = *(const bf16x8*)&Xs[ra * 128 + (kb ^ ((ra & 7) * 8))];
        bf16x8 AS1 = *(const bf16x8*)&Xs[rb * 128 + (kb ^ ((rb & 7) * 8))];
        bf16x8 AT0 = *(const bf16x8*)&Ht[ra * 128 + (kb ^ ((ra & 7) * 8))];
        bf16x8 AT1 = *(const bf16x8*)&Ht[rb * 128 + (kb ^ ((rb & 7) * 8))];
        #pragma unroll
        for (int nf = 0; nf < 8; ++nf) {
            const int e = nf * 16 + lrow;
            bf16x8 Bs = *(const bf16x8*)&Wsvb[e * 128 + kb];
            bf16x8 Bt = *(const bf16x8*)&Wtvb[e * 128 + kb];
            oS[0][nf] = __builtin_amdgcn_mfma_f32_16x16x32_bf16(AS0, Bs, oS[0][nf], 0, 0, 0);
            oS[1][nf] = __builtin_amdgcn_mfma_f32_16x16x32_bf16(AS1, Bs, oS[1][nf], 0, 0, 0);
            oT[0][nf] = __builtin_amdgcn_mfma_f32_16x16x32_bf16(AT0, Bt, oT[0][nf], 0, 0, 0);
            oT[1][nf] = __builtin_amdgcn_mfma_f32_16x16x32_bf16(AT1, Bt, oT[1][nf], 0, 0, 0);
        }
    }

    // epilogue: + bias, f32 nontemporal store (streaming, never re-read)
    float bvS[8], bvT[8];
    #pragma unroll
    for (int nf = 0; nf < 8; ++nf) {
        bvS[nf] = bsv[nf * 16 + lrow];
        bvT[nf] = btv[nf * 16 + lrow];
    }
    #pragma unroll
    for (int mf = 0; mf < 2; ++mf) {
        #pragma unroll
        for (int nf = 0; nf < 8; ++nf) {
            const int e = nf * 16 + lrow;
            #pragma unroll
            for (int j = 0; j < 4; ++j) {
                const int rt = r0 + mf * 16 + kg * 4 + j;
                const long off = (long)(m0 + rt) * 128 + e;
                __builtin_nontemporal_store(oT[mf][nf][j] + bvT[nf], outT + off);
                __builtin_nontemporal_store(oS[mf][nf][j] + bvS[nf], outS + off);
            }
        }
    }
}

// ---- copy body: each bank = 32,000,000 float4; 1000 chunks/bank of
// 32,000 float4 (256 threads x 125). cid in [0,2000).
__device__ __forceinline__ void copy_body(
    int cid, const float* __restrict__ mv1, const float* __restrict__ mv2,
    float* __restrict__ oM1, float* __restrict__ oM2)
{
    const bool bank2 = (cid >= 1000);
    const long base = (long)(bank2 ? cid - 1000 : cid) * 32000;
    const fvec4* src = (bank2 ? (const fvec4*)mv2 : (const fvec4*)mv1) + base;
    fvec4* dst = (bank2 ? (fvec4*)oM2 : (fvec4*)oM1) + base;
    const int t = threadIdx.x;
    // 125 float4 per thread; 5-deep load/store groups for MLP. mv2 loads cached
    // (L3-prefetch for the gather); mv1 loads + all stores nontemporal.
    #pragma unroll 1
    for (int i = 0; i < 125; i += 5) {
        fvec4 v[5];
        #pragma unroll
        for (int u = 0; u < 5; ++u) {
            const fvec4* p = src + (long)(i + u) * 256 + t;
            v[u] = bank2 ? *p : __builtin_nontemporal_load(p);
        }
        #pragma unroll
        for (int u = 0; u < 5; ++u)
            __builtin_nontemporal_store(v[u], dst + (long)(i + u) * 256 + t);
    }
}

// ---- mega kernel: bid%3==0 -> branch compute (1024), else bank copy (2000 + 48 idle).
// Interleaved ids keep both block types co-resident so the BW-bound copy
// hides the gather's HBM latency and the MFMA stages.
__global__ __launch_bounds__(256) void mega(
    const float* __restrict__ memv2, const int* __restrict__ idx,
    const float* __restrict__ aS, const float* __restrict__ aT,
    const unsigned short* __restrict__ wb,
    const float* __restrict__ bsv, const float* __restrict__ btv,
    float* __restrict__ outT, float* __restrict__ outS,
    const float* __restrict__ mv1,
    float* __restrict__ oM1, float* __restrict__ oM2)
{
    __shared__ unsigned short Xs[128 * 128];
    __shared__ unsigned short Ht[128 * 128];
    const int bid = blockIdx.x;
    const int r3 = bid % 3;
    if (r3 == 0) {
        branch_body(bid / 3, memv2, idx, aS, aT, wb, bsv, btv, outT, outS, Xs, Ht);
    } else {
        const int cid = (bid / 3) * 2 + (r3 - 1);
        if (cid < 2000)
            copy_body(cid, mv1, memv2, oM1, oM2);
    }
}

// ---- momentum update + L2-normalize the 256 touched rows (after the copy).
// numpy fancy-assignment semantics: for duplicate y, LAST occurrence wins.
__global__ void update_mem(const float* __restrict__ v1, const float* __restrict__ v2,
                           const int* __restrict__ y,
                           const float* __restrict__ m1, const float* __restrict__ m2,
                           float* __restrict__ o1, float* __restrict__ o2) {
    __shared__ int s_skip;
    __shared__ float part1[2], part2[2];
    const int b = blockIdx.x, t = threadIdx.x;   // 128 threads = 2 waves
    const int yb = y[b];
    if (t == 0) {
        int sk = 0;
        for (int b2 = b + 1; b2 < 256; ++b2) sk |= (y[b2] == yb);
        s_skip = sk;
    }
    __syncthreads();
    if (s_skip) return;
    float x1 = m1[(long)yb * 128 + t] * 0.5f + v1[b * 128 + t] * 0.5f;
    float x2 = m2[(long)yb * 128 + t] * 0.5f + v2[b * 128 + t] * 0.5f;
    float s1 = x1 * x1, s2 = x2 * x2;
    #pragma unroll
    for (int o = 32; o > 0; o >>= 1) {
        s1 += __shfl_down(s1, o);
        s2 += __shfl_down(s2, o);
    }
    if ((t & 63) == 0) { part1[t >> 6] = s1; part2[t >> 6] = s2; }
    __syncthreads();
    const float n1 = part1[0] + part1[1];
    const float n2 = part2[0] + part2[1];
    o1[(long)yb * 128 + t] = x1 / sqrtf(n1);
    o2[(long)yb * 128 + t] = x2 / sqrtf(n2);
}

extern "C" void kernel_launch(void* const* d_in, const int* in_sizes, int n_in,
                              void* d_out, int out_size, void* d_ws, size_t ws_size,
                              hipStream_t stream) {
    (void)in_sizes; (void)n_in; (void)out_size; (void)ws_size;
    const float* v1  = (const float*)d_in[0];
    const float* v2  = (const float*)d_in[1];
    const int*   y   = (const int*)d_in[2];
    const int*   idx = (const int*)d_in[3];
    const float* mv1 = (const float*)d_in[4];
    const float* mv2 = (const float*)d_in[5];
    const float* Ws1 = (const float*)d_in[6];
    const float* bs1 = (const float*)d_in[7];
    const float* Ws2 = (const float*)d_in[8];
    const float* bs2 = (const float*)d_in[9];
    const float* Wsv = (const float*)d_in[10];
    const float* bsv = (const float*)d_in[11];
    const float* Wt1 = (const float*)d_in[12];
    const float* bt1 = (const float*)d_in[13];
    const float* Wt2 = (const float*)d_in[14];
    const float* bt2 = (const float*)d_in[15];
    const float* Wtv = (const float*)d_in[16];
    const float* btv = (const float*)d_in[17];

    float* outT = (float*)d_out;                 // outs_t
    float* outS = outT + 16777216;               // outs_s
    float* oM1  = outT + 33554432;               // new_mem_v1
    float* oM2  = oM1 + 128000000;               // new_mem_v2

    float* aS = (float*)d_ws;                    // 32768 f32
    float* aT = aS + 32768;                      // 32768 f32
    unsigned short* wb = (unsigned short*)(aT + 32768);  // 4 * 16384 bf16

    prep_weights<<<64, 256, 0, stream>>>(Ws2, Wsv, Wt2, Wtv, wb);
    prep_a<<<256, 128, 0, stream>>>(v1, v2, Ws1, bs1, bs2, Wt1, bt1, bt2, aS, aT);
    mega<<<3072, 256, 0, stream>>>(mv2, idx, aS, aT, wb, bsv, btv, outT, outS,
                                   mv1, oM1, oM2);
    update_mem<<<256, 128, 0, stream>>>(v1, v2, y, mv1, mv2, oM1, oM2);
}

// Round 5
// 461.671 us; speedup vs baseline: 1.1554x; 1.0001x over previous
//
#include <hip/hip_runtime.h>

// RelationMemory: B=256, D=128, OUT=1e6, K+1=512, MOM=0.5
// d_out layout (f32): outs_t [512,256,128] | outs_s [512,256,128] | mem_v1 [1e6,128] | mem_v2 [1e6,128]

typedef __attribute__((ext_vector_type(8))) short bf16x8;
typedef __attribute__((ext_vector_type(4))) float f32x4;
typedef __attribute__((ext_vector_type(4))) float fvec4;  // native vec for nontemporal builtins

__device__ __forceinline__ unsigned short f2bf(float f) {
    union { float ff; unsigned u; } v; v.ff = f;
    unsigned u = v.u;
    u += 0x7fffu + ((u >> 16) & 1u);   // RNE
    return (unsigned short)(u >> 16);
}

// ---- convert the 4 inner weight matrices (f32 [128,128] row-major) to bf16 in ws
__global__ void prep_weights(const float* __restrict__ Ws2,
                             const float* __restrict__ Wsv,
                             const float* __restrict__ Wt2,
                             const float* __restrict__ Wtv,
                             unsigned short* __restrict__ wb) {
    int i = blockIdx.x * 256 + threadIdx.x;
    if (i < 16384) {
        wb[i]         = f2bf(Ws2[i]);
        wb[16384 + i] = f2bf(Wsv[i]);
        wb[32768 + i] = f2bf(Wt2[i]);
        wb[49152 + i] = f2bf(Wtv[i]);
    }
}

// ---- aS = v1@Ws1^T + bs1 - bs2 ; aT = v2@Wt1^T + bt1 - bt2   (exact f32)
__global__ void prep_a(const float* __restrict__ v1, const float* __restrict__ v2,
                       const float* __restrict__ Ws1, const float* __restrict__ bs1,
                       const float* __restrict__ bs2,
                       const float* __restrict__ Wt1, const float* __restrict__ bt1,
                       const float* __restrict__ bt2,
                       float* __restrict__ aS, float* __restrict__ aT) {
    __shared__ float vs1[128], vs2[128];
    const int b = blockIdx.x, e = threadIdx.x;
    vs1[e] = v1[b * 128 + e];
    vs2[e] = v2[b * 128 + e];
    __syncthreads();
    float s1 = 0.f, s2 = 0.f;
    const float4* w1 = (const float4*)(Ws1 + e * 128);
    const float4* w2 = (const float4*)(Wt1 + e * 128);
    #pragma unroll
    for (int d4 = 0; d4 < 32; ++d4) {
        float4 a = w1[d4], c = w2[d4];
        s1 += a.x * vs1[d4*4] + a.y * vs1[d4*4+1] + a.z * vs1[d4*4+2] + a.w * vs1[d4*4+3];
        s2 += c.x * vs2[d4*4] + c.y * vs2[d4*4+1] + c.z * vs2[d4*4+2] + c.w * vs2[d4*4+3];
    }
    aS[b * 128 + e] = s1 + bs1[e] - bs2[e];
    aT[b * 128 + e] = s2 + bt1[e] - bt2[e];
}

// ---- branch compute body: gather -> (X@W2^T) -> relu(a'-.) -> (H@Wv^T)+bv
__device__ __forceinline__ void branch_body(
    int blk,
    const float* __restrict__ memv2, const int* __restrict__ idx,
    const float* __restrict__ aS, const float* __restrict__ aT,
    const unsigned short* __restrict__ wb,
    const float* __restrict__ bsv, const float* __restrict__ btv,
    float* __restrict__ outT, float* __restrict__ outS,
    unsigned short* Xs, unsigned short* Ht)
{
    const int tid  = threadIdx.x;
    const int wv   = tid >> 6, lane = tid & 63;
    const int m0   = blk * 128;
    const int b0   = m0 & 255;        // batch base of this tile
    const int kq   = m0 >> 8;         // negatives-index (constant across tile)

    // gather phase: wave wv loads rows [wv*32, wv*32+32); 2 rows per wave-instr
    {
        const int sub = lane >> 5;
        const int c4  = (lane & 31) * 4;
        #pragma unroll
        for (int i = 0; i < 16; ++i) {
            const int r = wv * 32 + i * 2 + sub;
            const int grow = idx[(b0 + r) * 512 + kq];
            const float4 x = *(const float4*)(memv2 + (long)grow * 128 + c4);
            ushort4 u;
            u.x = f2bf(x.x); u.y = f2bf(x.y); u.z = f2bf(x.z); u.w = f2bf(x.w);
            // XOR-swizzle 16B chunks by row to make ds_read_b128 bank-uniform
            *(ushort4*)&Xs[r * 128 + (c4 ^ ((r & 7) * 8))] = u;
        }
    }
    __syncthreads();

    const int r0   = wv * 32;
    const int lrow = lane & 15;
    const int kg   = lane >> 4;

    const unsigned short* Ws2b = wb;
    const unsigned short* Wsvb = wb + 16384;
    const unsigned short* Wt2b = wb + 32768;
    const unsigned short* Wtvb = wb + 49152;

    f32x4 accS[2][8], accT[2][8];
    #pragma unroll
    for (int mf = 0; mf < 2; ++mf)
        #pragma unroll
        for (int nf = 0; nf < 8; ++nf) {
            accS[mf][nf] = (f32x4){0.f, 0.f, 0.f, 0.f};
            accT[mf][nf] = (f32x4){0.f, 0.f, 0.f, 0.f};
        }

    // stage 1: X @ W2^T for both branches (A frags shared)
    #pragma unroll
    for (int kk = 0; kk < 4; ++kk) {
        const int kb = kk * 32 + kg * 8;
        const int ra = r0 + lrow, rb = r0 + 16 + lrow;
        bf16x8 A0 = *(const bf16x8*)&Xs[ra * 128 + (kb ^ ((ra & 7) * 8))];
        bf16x8 A1 = *(const bf16x8*)&Xs[rb * 128 + (kb ^ ((rb & 7) * 8))];
        #pragma unroll
        for (int nf = 0; nf < 8; ++nf) {
            const int e = nf * 16 + lrow;
            bf16x8 Bs = *(const bf16x8*)&Ws2b[e * 128 + kb];
            bf16x8 Bt = *(const bf16x8*)&Wt2b[e * 128 + kb];
            accS[0][nf] = __builtin_amdgcn_mfma_f32_16x16x32_bf16(A0, Bs, accS[0][nf], 0, 0, 0);
            accS[1][nf] = __builtin_amdgcn_mfma_f32_16x16x32_bf16(A1, Bs, accS[1][nf], 0, 0, 0);
            accT[0][nf] = __builtin_amdgcn_mfma_f32_16x16x32_bf16(A0, Bt, accT[0][nf], 0, 0, 0);
            accT[1][nf] = __builtin_amdgcn_mfma_f32_16x16x32_bf16(A1, Bt, accT[1][nf], 0, 0, 0);
        }
    }
    __syncthreads();

    // relu(a' - acc) -> bf16 H tiles (H_s overwrites X; rows are wave-private)
    #pragma unroll
    for (int mf = 0; mf < 2; ++mf) {
        #pragma unroll
        for (int nf = 0; nf < 8; ++nf) {
            const int e = nf * 16 + lrow;
            #pragma unroll
            for (int j = 0; j < 4; ++j) {
                const int rt = r0 + mf * 16 + kg * 4 + j;   // m89-verified C/D layout
                const int b  = b0 + rt;
                float hS = fmaxf(aS[b * 128 + e] - accS[mf][nf][j], 0.f);
                float hT = fmaxf(aT[b * 128 + e] - accT[mf][nf][j], 0.f);
                const int ei = e ^ ((rt & 7) * 8);
                Xs[rt * 128 + ei] = f2bf(hS);
                Ht[rt * 128 + ei] = f2bf(hT);
            }
        }
    }
    __syncthreads();

    // stage 2: H @ Wv^T
    f32x4 oS[2][8], oT[2][8];
    #pragma unroll
    for (int mf = 0; mf < 2; ++mf)
        #pragma unroll
        for (int nf = 0; nf < 8; ++nf) {
            oS[mf][nf] = (f32x4){0.f, 0.f, 0.f, 0.f};
            oT[mf][nf] = (f32x4){0.f, 0.f, 0.f, 0.f};
        }
    #pragma unroll
    for (int kk = 0; kk < 4; ++kk) {
        const int kb = kk * 32 + kg * 8;
        const int ra = r0 + lrow, rb = r0 + 16 + lrow;
        bf16x8 AS0 = *(const bf16x8*)&Xs[ra * 128 + (kb ^ ((ra & 7) * 8))];
        bf16x8 AS1 = *(const bf16x8*)&Xs[rb * 128 + (kb ^ ((rb & 7) * 8))];
        bf16x8 AT0 = *(const bf16x8*)&Ht[ra * 128 + (kb ^ ((ra & 7) * 8))];
        bf16x8 AT1 = *(const bf16x8*)&Ht[rb * 128 + (kb ^ ((rb & 7) * 8))];
        #pragma unroll
        for (int nf = 0; nf < 8; ++nf) {
            const int e = nf * 16 + lrow;
            bf16x8 Bs = *(const bf16x8*)&Wsvb[e * 128 + kb];
            bf16x8 Bt = *(const bf16x8*)&Wtvb[e * 128 + kb];
            oS[0][nf] = __builtin_amdgcn_mfma_f32_16x16x32_bf16(AS0, Bs, oS[0][nf], 0, 0, 0);
            oS[1][nf] = __builtin_amdgcn_mfma_f32_16x16x32_bf16(AS1, Bs, oS[1][nf], 0, 0, 0);
            oT[0][nf] = __builtin_amdgcn_mfma_f32_16x16x32_bf16(AT0, Bt, oT[0][nf], 0, 0, 0);
            oT[1][nf] = __builtin_amdgcn_mfma_f32_16x16x32_bf16(AT1, Bt, oT[1][nf], 0, 0, 0);
        }
    }

    // epilogue: + bias, f32 nontemporal store (streaming, never re-read)
    float bvS[8], bvT[8];
    #pragma unroll
    for (int nf = 0; nf < 8; ++nf) {
        bvS[nf] = bsv[nf * 16 + lrow];
        bvT[nf] = btv[nf * 16 + lrow];
    }
    #pragma unroll
    for (int mf = 0; mf < 2; ++mf) {
        #pragma unroll
        for (int nf = 0; nf < 8; ++nf) {
            const int e = nf * 16 + lrow;
            #pragma unroll
            for (int j = 0; j < 4; ++j) {
                const int rt = r0 + mf * 16 + kg * 4 + j;
                const long off = (long)(m0 + rt) * 128 + e;
                __builtin_nontemporal_store(oT[mf][nf][j] + bvT[nf], outT + off);
                __builtin_nontemporal_store(oS[mf][nf][j] + bvS[nf], outS + off);
            }
        }
    }
}

// ---- copy body: each bank = 32,000,000 float4; 1000 chunks/bank of
// 32,000 float4 (256 threads x 125). cid in [0,2000).
__device__ __forceinline__ void copy_body(
    int cid, const float* __restrict__ mv1, const float* __restrict__ mv2,
    float* __restrict__ oM1, float* __restrict__ oM2)
{
    const bool bank2 = (cid >= 1000);
    const long base = (long)(bank2 ? cid - 1000 : cid) * 32000;
    const fvec4* src = (bank2 ? (const fvec4*)mv2 : (const fvec4*)mv1) + base;
    fvec4* dst = (bank2 ? (fvec4*)oM2 : (fvec4*)oM1) + base;
    const int t = threadIdx.x;
    // 125 float4 per thread; 5-deep load/store groups for MLP. mv2 loads cached
    // (L3-prefetch for the gather); mv1 loads + all stores nontemporal.
    #pragma unroll 1
    for (int i = 0; i < 125; i += 5) {
        fvec4 v[5];
        #pragma unroll
        for (int u = 0; u < 5; ++u) {
            const fvec4* p = src + (long)(i + u) * 256 + t;
            v[u] = bank2 ? *p : __builtin_nontemporal_load(p);
        }
        #pragma unroll
        for (int u = 0; u < 5; ++u)
            __builtin_nontemporal_store(v[u], dst + (long)(i + u) * 256 + t);
    }
}

// ---- mega kernel: bid%3==0 -> branch compute (1024), else bank copy (2000 + 48 idle).
// Interleaved ids keep both block types co-resident so the BW-bound copy
// hides the gather's HBM latency and the MFMA stages.
__global__ __launch_bounds__(256) void mega(
    const float* __restrict__ memv2, const int* __restrict__ idx,
    const float* __restrict__ aS, const float* __restrict__ aT,
    const unsigned short* __restrict__ wb,
    const float* __restrict__ bsv, const float* __restrict__ btv,
    float* __restrict__ outT, float* __restrict__ outS,
    const float* __restrict__ mv1,
    float* __restrict__ oM1, float* __restrict__ oM2)
{
    __shared__ unsigned short Xs[128 * 128];
    __shared__ unsigned short Ht[128 * 128];
    const int bid = blockIdx.x;
    const int r3 = bid % 3;
    if (r3 == 0) {
        branch_body(bid / 3, memv2, idx, aS, aT, wb, bsv, btv, outT, outS, Xs, Ht);
    } else {
        const int cid = (bid / 3) * 2 + (r3 - 1);
        if (cid < 2000)
            copy_body(cid, mv1, memv2, oM1, oM2);
    }
}

// ---- momentum update + L2-normalize the 256 touched rows (after the copy).
// numpy fancy-assignment semantics: for duplicate y, LAST occurrence wins.
__global__ void update_mem(const float* __restrict__ v1, const float* __restrict__ v2,
                           const int* __restrict__ y,
                           const float* __restrict__ m1, const float* __restrict__ m2,
                           float* __restrict__ o1, float* __restrict__ o2) {
    __shared__ int s_skip;
    __shared__ float part1[2], part2[2];
    const int b = blockIdx.x, t = threadIdx.x;   // 128 threads = 2 waves
    const int yb = y[b];
    if (t == 0) {
        int sk = 0;
        for (int b2 = b + 1; b2 < 256; ++b2) sk |= (y[b2] == yb);
        s_skip = sk;
    }
    __syncthreads();
    if (s_skip) return;
    float x1 = m1[(long)yb * 128 + t] * 0.5f + v1[b * 128 + t] * 0.5f;
    float x2 = m2[(long)yb * 128 + t] * 0.5f + v2[b * 128 + t] * 0.5f;
    float s1 = x1 * x1, s2 = x2 * x2;
    #pragma unroll
    for (int o = 32; o > 0; o >>= 1) {
        s1 += __shfl_down(s1, o);
        s2 += __shfl_down(s2, o);
    }
    if ((t & 63) == 0) { part1[t >> 6] = s1; part2[t >> 6] = s2; }
    __syncthreads();
    const float n1 = part1[0] + part1[1];
    const float n2 = part2[0] + part2[1];
    o1[(long)yb * 128 + t] = x1 / sqrtf(n1);
    o2[(long)yb * 128 + t] = x2 / sqrtf(n2);
}

extern "C" void kernel_launch(void* const* d_in, const int* in_sizes, int n_in,
                              void* d_out, int out_size, void* d_ws, size_t ws_size,
                              hipStream_t stream) {
    (void)in_sizes; (void)n_in; (void)out_size; (void)ws_size;
    const float* v1  = (const float*)d_in[0];
    const float* v2  = (const float*)d_in[1];
    const int*   y   = (const int*)d_in[2];
    const int*   idx = (const int*)d_in[3];
    const float* mv1 = (const float*)d_in[4];
    const float* mv2 = (const float*)d_in[5];
    const float* Ws1 = (const float*)d_in[6];
    const float* bs1 = (const float*)d_in[7];
    const float* Ws2 = (const float*)d_in[8];
    const float* bs2 = (const float*)d_in[9];
    const float* Wsv = (const float*)d_in[10];
    const float* bsv = (const float*)d_in[11];
    const float* Wt1 = (const float*)d_in[12];
    const float* bt1 = (const float*)d_in[13];
    const float* Wt2 = (const float*)d_in[14];
    const float* bt2 = (const float*)d_in[15];
    const float* Wtv = (const float*)d_in[16];
    const float* btv = (const float*)d_in[17];

    float* outT = (float*)d_out;                 // outs_t
    float* outS = outT + 16777216;               // outs_s
    float* oM1  = outT + 33554432;               // new_mem_v1
    float* oM2  = oM1 + 128000000;               // new_mem_v2

    float* aS = (float*)d_ws;                    // 32768 f32
    float* aT = aS + 32768;                      // 32768 f32
    unsigned short* wb = (unsigned short*)(aT + 32768);  // 4 * 16384 bf16

    prep_weights<<<64, 256, 0, stream>>>(Ws2, Wsv, Wt2, Wtv, wb);
    prep_a<<<256, 128, 0, stream>>>(v1, v2, Ws1, bs1, bs2, Wt1, bt1, bt2, aS, aT);
    mega<<<3072, 256, 0, stream>>>(mv2, idx, aS, aT, wb, bsv, btv, outT, outS,
                                   mv1, oM1, oM2);
    update_mem<<<256, 128, 0, stream>>>(v1, v2, y, mv1, mv2, oM1, oM2);
}

// Round 6
// 460.680 us; speedup vs baseline: 1.1579x; 1.0022x over previous
//
#include <hip/hip_runtime.h>

// RelationMemory: B=256, D=128, OUT=1e6, K+1=512, MOM=0.5
// d_out layout (f32): outs_t [512,256,128] | outs_s [512,256,128] | mem_v1 [1e6,128] | mem_v2 [1e6,128]

typedef __attribute__((ext_vector_type(8))) short bf16x8;
typedef __attribute__((ext_vector_type(4))) float f32x4;
typedef __attribute__((ext_vector_type(4))) float fvec4;  // native vec for nontemporal builtins

__device__ __forceinline__ unsigned short f2bf(float f) {
    union { float ff; unsigned u; } v; v.ff = f;
    unsigned u = v.u;
    u += 0x7fffu + ((u >> 16) & 1u);   // RNE
    return (unsigned short)(u >> 16);
}

// ---- convert the 4 inner weight matrices (f32 [128,128] row-major) to bf16 in ws
__global__ void prep_weights(const float* __restrict__ Ws2,
                             const float* __restrict__ Wsv,
                             const float* __restrict__ Wt2,
                             const float* __restrict__ Wtv,
                             unsigned short* __restrict__ wb) {
    int i = blockIdx.x * 256 + threadIdx.x;
    if (i < 16384) {
        wb[i]         = f2bf(Ws2[i]);
        wb[16384 + i] = f2bf(Wsv[i]);
        wb[32768 + i] = f2bf(Wt2[i]);
        wb[49152 + i] = f2bf(Wtv[i]);
    }
}

// ---- aS = v1@Ws1^T + bs1 - bs2 ; aT = v2@Wt1^T + bt1 - bt2   (exact f32)
__global__ void prep_a(const float* __restrict__ v1, const float* __restrict__ v2,
                       const float* __restrict__ Ws1, const float* __restrict__ bs1,
                       const float* __restrict__ bs2,
                       const float* __restrict__ Wt1, const float* __restrict__ bt1,
                       const float* __restrict__ bt2,
                       float* __restrict__ aS, float* __restrict__ aT) {
    __shared__ float vs1[128], vs2[128];
    const int b = blockIdx.x, e = threadIdx.x;
    vs1[e] = v1[b * 128 + e];
    vs2[e] = v2[b * 128 + e];
    __syncthreads();
    float s1 = 0.f, s2 = 0.f;
    const float4* w1 = (const float4*)(Ws1 + e * 128);
    const float4* w2 = (const float4*)(Wt1 + e * 128);
    #pragma unroll
    for (int d4 = 0; d4 < 32; ++d4) {
        float4 a = w1[d4], c = w2[d4];
        s1 += a.x * vs1[d4*4] + a.y * vs1[d4*4+1] + a.z * vs1[d4*4+2] + a.w * vs1[d4*4+3];
        s2 += c.x * vs2[d4*4] + c.y * vs2[d4*4+1] + c.z * vs2[d4*4+2] + c.w * vs2[d4*4+3];
    }
    aS[b * 128 + e] = s1 + bs1[e] - bs2[e];
    aT[b * 128 + e] = s2 + bt1[e] - bt2[e];
}

// ---- branch compute body: gather -> (X@W2^T) -> relu(a'-.) -> (H@Wv^T)+bv
__device__ __forceinline__ void branch_body(
    int blk,
    const float* __restrict__ memv2, const int* __restrict__ idx,
    const float* __restrict__ aS, const float* __restrict__ aT,
    const unsigned short* __restrict__ wb,
    const float* __restrict__ bsv, const float* __restrict__ btv,
    float* __restrict__ outT, float* __restrict__ outS,
    unsigned short* Xs, unsigned short* Ht)
{
    const int tid  = threadIdx.x;
    const int wv   = tid >> 6, lane = tid & 63;
    const int m0   = blk * 128;
    const int b0   = m0 & 255;        // batch base of this tile
    const int kq   = m0 >> 8;         // negatives-index (constant across tile)

    // gather phase: wave wv loads rows [wv*32, wv*32+32); 2 rows per wave-instr
    {
        const int sub = lane >> 5;
        const int c4  = (lane & 31) * 4;
        #pragma unroll
        for (int i = 0; i < 16; ++i) {
            const int r = wv * 32 + i * 2 + sub;
            const int grow = idx[(b0 + r) * 512 + kq];
            const float4 x = *(const float4*)(memv2 + (long)grow * 128 + c4);
            ushort4 u;
            u.x = f2bf(x.x); u.y = f2bf(x.y); u.z = f2bf(x.z); u.w = f2bf(x.w);
            // XOR-swizzle 16B chunks by row to make ds_read_b128 bank-uniform
            *(ushort4*)&Xs[r * 128 + (c4 ^ ((r & 7) * 8))] = u;
        }
    }
    __syncthreads();

    const int r0   = wv * 32;
    const int lrow = lane & 15;
    const int kg   = lane >> 4;

    const unsigned short* Ws2b = wb;
    const unsigned short* Wsvb = wb + 16384;
    const unsigned short* Wt2b = wb + 32768;
    const unsigned short* Wtvb = wb + 49152;

    f32x4 accS[2][8], accT[2][8];
    #pragma unroll
    for (int mf = 0; mf < 2; ++mf)
        #pragma unroll
        for (int nf = 0; nf < 8; ++nf) {
            accS[mf][nf] = (f32x4){0.f, 0.f, 0.f, 0.f};
            accT[mf][nf] = (f32x4){0.f, 0.f, 0.f, 0.f};
        }

    // stage 1: X @ W2^T for both branches (A frags shared)
    #pragma unroll
    for (int kk = 0; kk < 4; ++kk) {
        const int kb = kk * 32 + kg * 8;
        const int ra = r0 + lrow, rb = r0 + 16 + lrow;
        bf16x8 A0 = *(const bf16x8*)&Xs[ra * 128 + (kb ^ ((ra & 7) * 8))];
        bf16x8 A1 = *(const bf16x8*)&Xs[rb * 128 + (kb ^ ((rb & 7) * 8))];
        #pragma unroll
        for (int nf = 0; nf < 8; ++nf) {
            const int e = nf * 16 + lrow;
            bf16x8 Bs = *(const bf16x8*)&Ws2b[e * 128 + kb];
            bf16x8 Bt = *(const bf16x8*)&Wt2b[e * 128 + kb];
            accS[0][nf] = __builtin_amdgcn_mfma_f32_16x16x32_bf16(A0, Bs, accS[0][nf], 0, 0, 0);
            accS[1][nf] = __builtin_amdgcn_mfma_f32_16x16x32_bf16(A1, Bs, accS[1][nf], 0, 0, 0);
            accT[0][nf] = __builtin_amdgcn_mfma_f32_16x16x32_bf16(A0, Bt, accT[0][nf], 0, 0, 0);
            accT[1][nf] = __builtin_amdgcn_mfma_f32_16x16x32_bf16(A1, Bt, accT[1][nf], 0, 0, 0);
        }
    }
    __syncthreads();

    // relu(a' - acc) -> bf16 H tiles (H_s overwrites X; rows are wave-private)
    #pragma unroll
    for (int mf = 0; mf < 2; ++mf) {
        #pragma unroll
        for (int nf = 0; nf < 8; ++nf) {
            const int e = nf * 16 + lrow;
            #pragma unroll
            for (int j = 0; j < 4; ++j) {
                const int rt = r0 + mf * 16 + kg * 4 + j;   // m89-verified C/D layout
                const int b  = b0 + rt;
                float hS = fmaxf(aS[b * 128 + e] - accS[mf][nf][j], 0.f);
                float hT = fmaxf(aT[b * 128 + e] - accT[mf][nf][j], 0.f);
                const int ei = e ^ ((rt & 7) * 8);
                Xs[rt * 128 + ei] = f2bf(hS);
                Ht[rt * 128 + ei] = f2bf(hT);
            }
        }
    }
    __syncthreads();

    // stage 2: H @ Wv^T
    f32x4 oS[2][8], oT[2][8];
    #pragma unroll
    for (int mf = 0; mf < 2; ++mf)
        #pragma unroll
        for (int nf = 0; nf < 8; ++nf) {
            oS[mf][nf] = (f32x4){0.f, 0.f, 0.f, 0.f};
            oT[mf][nf] = (f32x4){0.f, 0.f, 0.f, 0.f};
        }
    #pragma unroll
    for (int kk = 0; kk < 4; ++kk) {
        const int kb = kk * 32 + kg * 8;
        const int ra = r0 + lrow, rb = r0 + 16 + lrow;
        bf16x8 AS0 = *(const bf16x8*)&Xs[ra * 128 + (kb ^ ((ra & 7) * 8))];
        bf16x8 AS1 = *(const bf16x8*)&Xs[rb * 128 + (kb ^ ((rb & 7) * 8))];
        bf16x8 AT0 = *(const bf16x8*)&Ht[ra * 128 + (kb ^ ((ra & 7) * 8))];
        bf16x8 AT1 = *(const bf16x8*)&Ht[rb * 128 + (kb ^ ((rb & 7) * 8))];
        #pragma unroll
        for (int nf = 0; nf < 8; ++nf) {
            const int e = nf * 16 + lrow;
            bf16x8 Bs = *(const bf16x8*)&Wsvb[e * 128 + kb];
            bf16x8 Bt = *(const bf16x8*)&Wtvb[e * 128 + kb];
            oS[0][nf] = __builtin_amdgcn_mfma_f32_16x16x32_bf16(AS0, Bs, oS[0][nf], 0, 0, 0);
            oS[1][nf] = __builtin_amdgcn_mfma_f32_16x16x32_bf16(AS1, Bs, oS[1][nf], 0, 0, 0);
            oT[0][nf] = __builtin_amdgcn_mfma_f32_16x16x32_bf16(AT0, Bt, oT[0][nf], 0, 0, 0);
            oT[1][nf] = __builtin_amdgcn_mfma_f32_16x16x32_bf16(AT1, Bt, oT[1][nf], 0, 0, 0);
        }
    }

    // epilogue: + bias, f32 nontemporal store (streaming, never re-read)
    float bvS[8], bvT[8];
    #pragma unroll
    for (int nf = 0; nf < 8; ++nf) {
        bvS[nf] = bsv[nf * 16 + lrow];
        bvT[nf] = btv[nf * 16 + lrow];
    }
    #pragma unroll
    for (int mf = 0; mf < 2; ++mf) {
        #pragma unroll
        for (int nf = 0; nf < 8; ++nf) {
            const int e = nf * 16 + lrow;
            #pragma unroll
            for (int j = 0; j < 4; ++j) {
                const int rt = r0 + mf * 16 + kg * 4 + j;
                const long off = (long)(m0 + rt) * 128 + e;
                __builtin_nontemporal_store(oT[mf][nf][j] + bvT[nf], outT + off);
                __builtin_nontemporal_store(oS[mf][nf][j] + bvS[nf], outS + off);
            }
        }
    }
}

// ---- copy body: each bank = 32,000,000 float4; 1000 chunks/bank of
// 32,000 float4 (256 threads x 125). cid in [0,2000).
__device__ __forceinline__ void copy_body(
    int cid, const float* __restrict__ mv1, const float* __restrict__ mv2,
    float* __restrict__ oM1, float* __restrict__ oM2)
{
    const bool bank2 = (cid >= 1000);
    const long base = (long)(bank2 ? cid - 1000 : cid) * 32000;
    const fvec4* src = (bank2 ? (const fvec4*)mv2 : (const fvec4*)mv1) + base;
    fvec4* dst = (bank2 ? (fvec4*)oM2 : (fvec4*)oM1) + base;
    const int t = threadIdx.x;
    // 125 float4 per thread; 5-deep load/store groups for MLP. mv2 loads cached
    // (L3-prefetch for the gather); mv1 loads + all stores nontemporal.
    #pragma unroll 1
    for (int i = 0; i < 125; i += 5) {
        fvec4 v[5];
        #pragma unroll
        for (int u = 0; u < 5; ++u) {
            const fvec4* p = src + (long)(i + u) * 256 + t;
            v[u] = bank2 ? *p : __builtin_nontemporal_load(p);
        }
        #pragma unroll
        for (int u = 0; u < 5; ++u)
            __builtin_nontemporal_store(v[u], dst + (long)(i + u) * 256 + t);
    }
}

// ---- mega kernel: bid%3==0 -> branch compute (1024), else bank copy (2000 + 48 idle).
// Interleaved ids keep both block types co-resident so the BW-bound copy
// hides the gather's HBM latency and the MFMA stages.
__global__ __launch_bounds__(256) void mega(
    const float* __restrict__ memv2, const int* __restrict__ idx,
    const float* __restrict__ aS, const float* __restrict__ aT,
    const unsigned short* __restrict__ wb,
    const float* __restrict__ bsv, const float* __restrict__ btv,
    float* __restrict__ outT, float* __restrict__ outS,
    const float* __restrict__ mv1,
    float* __restrict__ oM1, float* __restrict__ oM2)
{
    __shared__ unsigned short Xs[128 * 128];
    __shared__ unsigned short Ht[128 * 128];
    const int bid = blockIdx.x;
    const int r3 = bid % 3;
    if (r3 == 0) {
        branch_body(bid / 3, memv2, idx, aS, aT, wb, bsv, btv, outT, outS, Xs, Ht);
    } else {
        const int cid = (bid / 3) * 2 + (r3 - 1);
        if (cid < 2000)
            copy_body(cid, mv1, memv2, oM1, oM2);
    }
}

// ---- momentum update + L2-normalize the 256 touched rows (after the copy).
// numpy fancy-assignment semantics: for duplicate y, LAST occurrence wins.
__global__ void update_mem(const float* __restrict__ v1, const float* __restrict__ v2,
                           const int* __restrict__ y,
                           const float* __restrict__ m1, const float* __restrict__ m2,
                           float* __restrict__ o1, float* __restrict__ o2) {
    __shared__ int s_skip;
    __shared__ float part1[2], part2[2];
    const int b = blockIdx.x, t = threadIdx.x;   // 128 threads = 2 waves
    const int yb = y[b];
    if (t == 0) {
        int sk = 0;
        for (int b2 = b + 1; b2 < 256; ++b2) sk |= (y[b2] == yb);
        s_skip = sk;
    }
    __syncthreads();
    if (s_skip) return;
    float x1 = m1[(long)yb * 128 + t] * 0.5f + v1[b * 128 + t] * 0.5f;
    float x2 = m2[(long)yb * 128 + t] * 0.5f + v2[b * 128 + t] * 0.5f;
    float s1 = x1 * x1, s2 = x2 * x2;
    #pragma unroll
    for (int o = 32; o > 0; o >>= 1) {
        s1 += __shfl_down(s1, o);
        s2 += __shfl_down(s2, o);
    }
    if ((t & 63) == 0) { part1[t >> 6] = s1; part2[t >> 6] = s2; }
    __syncthreads();
    const float n1 = part1[0] + part1[1];
    const float n2 = part2[0] + part2[1];
    o1[(long)yb * 128 + t] = x1 / sqrtf(n1);
    o2[(long)yb * 128 + t] = x2 / sqrtf(n2);
}

extern "C" void kernel_launch(void* const* d_in, const int* in_sizes, int n_in,
                              void* d_out, int out_size, void* d_ws, size_t ws_size,
                              hipStream_t stream) {
    (void)in_sizes; (void)n_in; (void)out_size; (void)ws_size;
    const float* v1  = (const float*)d_in[0];
    const float* v2  = (const float*)d_in[1];
    const int*   y   = (const int*)d_in[2];
    const int*   idx = (const int*)d_in[3];
    const float* mv1 = (const float*)d_in[4];
    const float* mv2 = (const float*)d_in[5];
    const float* Ws1 = (const float*)d_in[6];
    const float* bs1 = (const float*)d_in[7];
    const float* Ws2 = (const float*)d_in[8];
    const float* bs2 = (const float*)d_in[9];
    const float* Wsv = (const float*)d_in[10];
    const float* bsv = (const float*)d_in[11];
    const float* Wt1 = (const float*)d_in[12];
    const float* bt1 = (const float*)d_in[13];
    const float* Wt2 = (const float*)d_in[14];
    const float* bt2 = (const float*)d_in[15];
    const float* Wtv = (const float*)d_in[16];
    const float* btv = (const float*)d_in[17];

    float* outT = (float*)d_out;                 // outs_t
    float* outS = outT + 16777216;               // outs_s
    float* oM1  = outT + 33554432;               // new_mem_v1
    float* oM2  = oM1 + 128000000;               // new_mem_v2

    float* aS = (float*)d_ws;                    // 32768 f32
    float* aT = aS + 32768;                      // 32768 f32
    unsigned short* wb = (unsigned short*)(aT + 32768);  // 4 * 16384 bf16

    prep_weights<<<64, 256, 0, stream>>>(Ws2, Wsv, Wt2, Wtv, wb);
    prep_a<<<256, 128, 0, stream>>>(v1, v2, Ws1, bs1, bs2, Wt1, bt1, bt2, aS, aT);
    mega<<<3072, 256, 0, stream>>>(mv2, idx, aS, aT, wb, bsv, btv, outT, outS,
                                   mv1, oM1, oM2);
    update_mem<<<256, 128, 0, stream>>>(v1, v2, y, mv1, mv2, oM1, oM2);
}